// Round 7
// baseline (135.584 us; speedup 1.0000x reference)
//
#include <hip/hip_runtime.h>
#include <math.h>

#define NROWS 4096
#define NCOLS 32000
#define NV4   8000          // float4 per row
#define BLOCK 1024
#define EPSF  1e-10f

typedef float floatx4 __attribute__((ext_vector_type(4)));

__device__ __forceinline__ float wave_reduce_sum(float v) {
#pragma unroll
  for (int o = 32; o > 0; o >>= 1) v += __shfl_down(v, o, 64);
  return v;
}

// One block per row, single streaming pass. Mask (p_i < p_lab) == (e_i <
// e_lab) is scale-invariant; the masked log1p series factorizes into power
// sums S1..S4 of e -> no staging, no second pass. Nontemporal loads (pure
// stream). This round: 2 super-iterations x 4 back-to-back independent
// loads for MLP (4-deep fits the 64-VGPR cap; 16-deep spilled in round 4).
__global__ __launch_bounds__(BLOCK, 8)
void weak_loss_main(const float* __restrict__ scores,
                    const int* __restrict__ labels,
                    float* __restrict__ out) {
  __shared__ float wred[16][5];

  const int row  = blockIdx.x;
  const int t    = threadIdx.x;
  const int lane = t & 63;
  const int wid  = t >> 6;

  const floatx4* __restrict__ rp4 = (const floatx4*)(scores + (size_t)row * NCOLS);
  const float e_lab = __expf(scores[(size_t)row * NCOLS + labels[row]]);

  float dsum = 0.0f, S1 = 0.0f, S2 = 0.0f, S3 = 0.0f, S4 = 0.0f;

#pragma unroll
  for (int b = 0; b < 2; ++b) {
    floatx4 v[4];
#pragma unroll
    for (int k = 0; k < 4; ++k) {
      const int kk  = b * 4 + k;
      const int idx = t + kk * BLOCK;          // max 1023 + 7*1024 = 8191
      if (kk < 7) {
        v[k] = __builtin_nontemporal_load(&rp4[idx]);   // always in range
      } else if (idx < NV4) {
        v[k] = __builtin_nontemporal_load(&rp4[idx]);
      } else {
        v[k] = (floatx4){-INFINITY, -INFINITY, -INFINITY, -INFINITY};
      }
    }
#pragma unroll
    for (int k = 0; k < 4; ++k) {
      float ev[4] = {__expf(v[k].x), __expf(v[k].y), __expf(v[k].z), __expf(v[k].w)};
#pragma unroll
      for (int m = 0; m < 4; ++m) {
        float e = ev[m];                       // exp(-inf) = 0 for padding
        dsum += e;
        float em = (e < e_lab) ? e : 0.0f;     // masked value
        float e2 = em * em;
        S1 += em;
        S2 += e2;
        S3 += e2 * em;
        S4 += e2 * e2;
      }
    }
  }

  // ---- Block reduction of {d, S1..S4} ----
  float vals[5] = {dsum, S1, S2, S3, S4};
#pragma unroll
  for (int k = 0; k < 5; ++k) {
    float r = wave_reduce_sum(vals[k]);
    if (lane == 0) wred[wid][k] = r;
  }
  __syncthreads();
  if (wid == 0) {
    float r[5];
#pragma unroll
    for (int k = 0; k < 5; ++k) {
      float v = (lane < 16) ? wred[lane][k] : 0.0f;
      r[k] = wave_reduce_sum(v);
    }
    if (lane == 0) {
      // loss_row = q*S1 + q^2*S2/2 + q^3*S3/3 + q^4*S4/4,  q = 1/(d+eps)
      float q  = 1.0f / (r[0] + EPSF);
      float q2 = q * q;
      float loss = q * r[1] + 0.5f * q2 * r[2]
                 + (1.0f / 3.0f) * q2 * q * r[3] + 0.25f * q2 * q2 * r[4];
      atomicAdd(out, loss * (1.0f / (float)NROWS));
    }
  }
}

extern "C" void kernel_launch(void* const* d_in, const int* in_sizes, int n_in,
                              void* d_out, int out_size, void* d_ws, size_t ws_size,
                              hipStream_t stream) {
  const float* scores = (const float*)d_in[0];
  const int*   labels = (const int*)d_in[1];
  float*       out    = (float*)d_out;

  (void)hipMemsetAsync(out, 0, sizeof(float), stream);  // capture-safe memset node
  weak_loss_main<<<NROWS, BLOCK, 0, stream>>>(scores, labels, out);
}

// Round 8
// 97.249 us; speedup vs baseline: 1.3942x; 1.3942x over previous
//
#include <hip/hip_runtime.h>

#define NROWS 4096
#define NCOLS 32000
#define NV4   8000          // float4 per row
#define BLOCK 1024
#define EPSF  1e-10f

typedef float floatx4 __attribute__((ext_vector_type(4)));

__device__ __forceinline__ float wave_reduce_sum(float v) {
#pragma unroll
  for (int o = 32; o > 0; o >>= 1) v += __shfl_down(v, o, 64);
  return v;
}

// One block per row, single streaming pass (round-6 structure — best
// measured: 99.1 µs, 5.4 TB/s effective read). Mask (p_i < p_lab) ==
// (e_i < e_lab) is scale-invariant; the masked log1p series factorizes
// into power sums S1..S4 of e -> no staging, no second pass. Nontemporal
// loads (pure stream, skip L2/L3 allocation: +7.8% over cached loads).
// NOTE: manual load batching (4-deep r7, 16-deep r4) REGRESSES — the
// compiler's software pipelining of this simple unroll-2 loop wins under
// the 64-VGPR launch-bounds cap. Do not re-batch.
__global__ __launch_bounds__(BLOCK, 8)
void weak_loss_main(const float* __restrict__ scores,
                    const int* __restrict__ labels,
                    float* __restrict__ out) {
  __shared__ float wred[16][5];

  const int row  = blockIdx.x;
  const int t    = threadIdx.x;
  const int lane = t & 63;
  const int wid  = t >> 6;

  const floatx4* __restrict__ rp4 = (const floatx4*)(scores + (size_t)row * NCOLS);
  const float e_lab = __expf(scores[(size_t)row * NCOLS + labels[row]]);

  float dsum = 0.0f, S1 = 0.0f, S2 = 0.0f, S3 = 0.0f, S4 = 0.0f;

#pragma unroll 2
  for (int j = t; j < NV4; j += BLOCK) {
    floatx4 v = __builtin_nontemporal_load(&rp4[j]);
    float ev[4];
    ev[0] = __expf(v.x);
    ev[1] = __expf(v.y);
    ev[2] = __expf(v.z);
    ev[3] = __expf(v.w);
#pragma unroll
    for (int k = 0; k < 4; ++k) {
      float e = ev[k];
      dsum += e;
      float em = (e < e_lab) ? e : 0.0f;   // masked value (0 kills all terms)
      float e2 = em * em;
      S1 += em;
      S2 += e2;
      S3 += e2 * em;
      S4 += e2 * e2;
    }
  }

  // ---- Block reduction of {d, S1..S4} ----
  float vals[5] = {dsum, S1, S2, S3, S4};
#pragma unroll
  for (int k = 0; k < 5; ++k) {
    float r = wave_reduce_sum(vals[k]);
    if (lane == 0) wred[wid][k] = r;
  }
  __syncthreads();
  if (wid == 0) {
    float r[5];
#pragma unroll
    for (int k = 0; k < 5; ++k) {
      float v = (lane < 16) ? wred[lane][k] : 0.0f;
      r[k] = wave_reduce_sum(v);
    }
    if (lane == 0) {
      // loss_row = q*S1 + q^2*S2/2 + q^3*S3/3 + q^4*S4/4,  q = 1/(d+eps)
      float q  = 1.0f / (r[0] + EPSF);
      float q2 = q * q;
      float loss = q * r[1] + 0.5f * q2 * r[2]
                 + (1.0f / 3.0f) * q2 * q * r[3] + 0.25f * q2 * q2 * r[4];
      atomicAdd(out, loss * (1.0f / (float)NROWS));
    }
  }
}

extern "C" void kernel_launch(void* const* d_in, const int* in_sizes, int n_in,
                              void* d_out, int out_size, void* d_ws, size_t ws_size,
                              hipStream_t stream) {
  const float* scores = (const float*)d_in[0];
  const int*   labels = (const int*)d_in[1];
  float*       out    = (float*)d_out;

  (void)hipMemsetAsync(out, 0, sizeof(float), stream);  // capture-safe memset node
  weak_loss_main<<<NROWS, BLOCK, 0, stream>>>(scores, labels, out);
}